// Round 12
// baseline (1000.789 us; speedup 1.0000x reference)
//
#include <hip/hip_runtime.h>
#include <cstdint>
#include <cstddef>

#define S_TOK 8192
#define DM    1024
#define NE    16
#define NF    4096
#define CAP   512

typedef __attribute__((ext_vector_type(8))) short bf16x8;
typedef __attribute__((ext_vector_type(4))) float f32x4;

__device__ __forceinline__ unsigned short f2bf(float f) {
  __bf16 b = (__bf16)f;
  return __builtin_bit_cast(unsigned short, b);
}
__device__ __forceinline__ unsigned pk2(float a, float b) {
  return (unsigned)f2bf(a) | ((unsigned)f2bf(b) << 16);
}
// bank-spread for the B [kg][col][16B] LDS layout
__device__ __forceinline__ int pcol(int c) { return c ^ ((c >> 3) & 7); }

__device__ __forceinline__ void gload_lds16(const void* g, void* l) {
  __builtin_amdgcn_global_load_lds(
      (const __attribute__((address_space(1))) void*)g,
      (__attribute__((address_space(3))) void*)l, 16, 0, 0);
}

// ---------------- fast zero of d_out ------------------------------------
__global__ void __launch_bounds__(256)
zero_kernel(float4* __restrict__ Out, int n4) {
  const int stride = gridDim.x * 256;
  for (int i = blockIdx.x * 256 + threadIdx.x; i < n4; i += stride)
    Out[i] = float4{0.f, 0.f, 0.f, 0.f};
}

// ---------------- gating: logits fp32, softmax, argmax -----------------
__global__ void __launch_bounds__(256)
gate_kernel(const float* __restrict__ X, const float* __restrict__ Wg,
            int* __restrict__ idx, float* __restrict__ gval) {
  const int tid  = threadIdx.x;
  const int lane = tid & 63;
  const int wid  = tid >> 6;
  const int e = lane & 15, q = lane >> 4;
  const int t0 = blockIdx.x * 16 + wid * 4;
  const int mbase = q * 256;

  const float* xp0 = X + (size_t)(t0 + 0) * DM + mbase;
  const float* xp1 = X + (size_t)(t0 + 1) * DM + mbase;
  const float* xp2 = X + (size_t)(t0 + 2) * DM + mbase;
  const float* xp3 = X + (size_t)(t0 + 3) * DM + mbase;
  const float* wp  = Wg + (size_t)mbase * NE + e;

  float a0 = 0.f, a1 = 0.f, a2 = 0.f, a3 = 0.f;
#pragma unroll 4
  for (int i = 0; i < 64; ++i) {
    float4 x0 = *(const float4*)(xp0 + i * 4);
    float4 x1 = *(const float4*)(xp1 + i * 4);
    float4 x2 = *(const float4*)(xp2 + i * 4);
    float4 x3 = *(const float4*)(xp3 + i * 4);
    float w0 = wp[(i * 4 + 0) * NE];
    float w1 = wp[(i * 4 + 1) * NE];
    float w2 = wp[(i * 4 + 2) * NE];
    float w3 = wp[(i * 4 + 3) * NE];
    a0 = fmaf(x0.x, w0, fmaf(x0.y, w1, fmaf(x0.z, w2, fmaf(x0.w, w3, a0))));
    a1 = fmaf(x1.x, w0, fmaf(x1.y, w1, fmaf(x1.z, w2, fmaf(x1.w, w3, a1))));
    a2 = fmaf(x2.x, w0, fmaf(x2.y, w1, fmaf(x2.z, w2, fmaf(x2.w, w3, a2))));
    a3 = fmaf(x3.x, w0, fmaf(x3.y, w1, fmaf(x3.z, w2, fmaf(x3.w, w3, a3))));
  }
#pragma unroll
  for (int s = 16; s < 64; s <<= 1) {
    a0 += __shfl_xor(a0, s, 64);
    a1 += __shfl_xor(a1, s, 64);
    a2 += __shfl_xor(a2, s, 64);
    a3 += __shfl_xor(a3, s, 64);
  }
  float l = (q == 0) ? a0 : (q == 1) ? a1 : (q == 2) ? a2 : a3;
  float bv = l; int bi = e;
#pragma unroll
  for (int s = 1; s < 16; s <<= 1) {
    float ov = __shfl_xor(bv, s, 16);
    int   oi = __shfl_xor(bi, s, 16);
    if (ov > bv || (ov == bv && oi < bi)) { bv = ov; bi = oi; }
  }
  float p  = expf(l - bv);
  float sm = p;
#pragma unroll
  for (int s = 1; s < 16; s <<= 1) sm += __shfl_xor(sm, s, 16);
  if (e == 0) {
    idx[t0 + q]  = bi;
    gval[t0 + q] = 1.0f / sm;
  }
}

// ---------------- routing scan: capacity-limited slot assignment -------
__global__ void __launch_bounds__(1024)
scan_kernel(const int* __restrict__ idx, int* __restrict__ s2t) {
  const int tid = threadIdx.x;
#pragma unroll
  for (int k = 0; k < 8; ++k) s2t[tid + k * 1024] = -1;
  __shared__ int base[16];
  __shared__ int wavecnt[16][16];
  if (tid < 16) base[tid] = 0;
  __syncthreads();
  const int wid = tid >> 6, lane = tid & 63;
  const unsigned long long ltmask = (1ull << lane) - 1ull;
  for (int c = 0; c < 8; ++c) {
    const int t = c * 1024 + tid;
    const int e = idx[t];
    int rank = 0;
#pragma unroll
    for (int ee = 0; ee < 16; ++ee) {
      unsigned long long m = __ballot(e == ee);
      if (lane == 0) wavecnt[wid][ee] = __popcll(m);
      if (ee == e) rank = __popcll(m & ltmask);
    }
    __syncthreads();
    if (tid < 16) {
      int s = base[tid];
#pragma unroll
      for (int w = 0; w < 16; ++w) { int cc = wavecnt[w][tid]; wavecnt[w][tid] = s; s += cc; }
      base[tid] = s;
    }
    __syncthreads();
    const int loc = wavecnt[wid][e] + rank;
    if (loc < CAP) s2t[e * CAP + loc] = t;
    __syncthreads();
  }
}

// ---------------- gather + cvt: X fp32 rows -> blocked gathered bf16 ----
// Xg layout: [e][kt(16)][kg(8)][slot(512)][16B]; 1 MB/expert, 16 MB.
__global__ void __launch_bounds__(256)
gather_kernel(const float* __restrict__ X, const int* __restrict__ s2t,
              unsigned short* __restrict__ Xg) {
  const int tid = threadIdx.x;
  const int d  = tid & 127;           // 8 floats per thread
  const int sl = tid >> 7;            // 0..1
  const int s0 = blockIdx.x * 16;     // 16 slots per block
#pragma unroll 2
  for (int p = 0; p < 8; ++p) {
    const int s = s0 + p * 2 + sl;
    const int tok = s2t[s];
    uint4 w;
    if (tok >= 0) {
      const float* xp = X + (size_t)tok * DM + d * 8;
      float4 v0 = *(const float4*)xp;
      float4 v1 = *(const float4*)(xp + 4);
      w = make_uint4(pk2(v0.x, v0.y), pk2(v0.z, v0.w),
                     pk2(v1.x, v1.y), pk2(v1.z, v1.w));
    } else {
      w = make_uint4(0u, 0u, 0u, 0u);
    }
    char* dst = (char*)Xg + (size_t)(s >> 9) * 1048576 +
                (size_t)(d >> 3) * 65536 + (size_t)(d & 7) * 8192 +
                (size_t)(s & 511) * 16;
    *(uint4*)dst = w;
  }
}

// H2 layout: [e][kt(64)][kg(8)][row(512)][8 bf16]; per-expert 4 MB.

// =======================================================================
// GEMM skeleton R12: 128x128 tile, BK=64, 256 thr (4 waves, 2Mx2N),
// LDS 48 KB (A dbuf 2x16 KB @0/@16384 via gload_lds; B single 16 KB
// @32768) -> 3 blocks/CU (m97 occupancy regime: inter-block overlap
// hides prologue/epilogue/stalls). Two raw barriers/iter; NO vmcnt(0)
// in the loop: B reg ping-pong depth-2 (bP/bQ, x2 unroll), A depth-1,
// counted vmcnt(12) retires A(kt+1) with 12 newer loads in flight.
// =======================================================================

// ---------------- GEMM1: H2[e] = relu(Xg[e] @ w1[e]) -------------------
#define G1_BX 4
#define G1_BY 32
#define G1_BZ 16
__global__ void __launch_bounds__(256, 3)
gemm1_kernel(const unsigned short* __restrict__ Xg, const float* __restrict__ W1,
             unsigned short* __restrict__ H2) {
  constexpr int NT = DM / 64;   // 16
  constexpr int NTM = NT - 1;
  __shared__ __align__(16) char lds[49152];

  const int tid = threadIdx.x;
  const int lane = tid & 63, wid = tid >> 6;
  const int wr = wid >> 1, wc = wid & 1;
  const int ln15 = lane & 15, l16 = lane >> 4;

  const int flat = blockIdx.x + G1_BX * (blockIdx.y + G1_BY * blockIdx.z);
  const int xcd = flat & 7, jj = flat >> 3;      // jj 0..255
  const int e  = xcd * 2 + (jj >> 7);
  const int rr = jj & 127;
  const int by = rr >> 2, bx = rr & 3;
  const int m0 = bx * 128, n0 = by * 128;

  char* const Bs = lds + 32768;

  // A: wave covers rows rb*64+lane (rb=wid>>1), kg = kgw..kgw+3
  const int rb = wid >> 1;
  const int kgw = (wid & 1) * 4;
  const int adst = kgw * 2048 + rb * 1024;
  const char* const aSrc = (const char*)Xg + (size_t)e * 1048576 +
                           (size_t)(m0 + rb * 64 + lane) * 16;

  // B: cols c0..c0+3, k-rows kq*8..kq*8+7
  const int c0 = (tid & 31) * 4;
  const int kq = tid >> 5;                       // 0..7
  const float* const bsrc = W1 + (size_t)e * DM * NF + (size_t)(kq * 8) * NF + n0 + c0;
  int bwoff[4];
#pragma unroll
  for (int cc = 0; cc < 4; ++cc) bwoff[cc] = 32768 + kq * 2048 + pcol(c0 + cc) * 16;

  int aoff[4], boff[4];
#pragma unroll
  for (int mi = 0; mi < 4; ++mi)
    aoff[mi] = l16 * 2048 + (wr * 64 + mi * 16 + ln15) * 16;
#pragma unroll
  for (int ni = 0; ni < 4; ++ni)
    boff[ni] = 32768 + l16 * 2048 + pcol(wc * 64 + ni * 16 + ln15) * 16;

  f32x4 acc[4][4];
#pragma unroll
  for (int mi = 0; mi < 4; ++mi)
#pragma unroll
    for (int ni = 0; ni < 4; ++ni) acc[mi][ni] = f32x4{0.f, 0.f, 0.f, 0.f};

  float4 bP[8], bQ[8];

  auto ISSUE_B = [&](float4* br, int kt) {
    const float* bp = bsrc + (size_t)kt * 64 * NF;
#pragma unroll
    for (int r = 0; r < 8; ++r) br[r] = *(const float4*)(bp + (size_t)r * NF);
  };
  auto ISSUE_A = [&](int Aoff, int kt) {
#pragma unroll
    for (int j = 0; j < 4; ++j)
      gload_lds16(aSrc + (size_t)kt * 65536 + (size_t)(kgw + j) * 8192,
                  lds + Aoff + adst + j * 2048);
  };
  auto WRITEB = [&](const float4* br) {
    const float* f = (const float*)br;
#pragma unroll
    for (int cc = 0; cc < 4; ++cc)
      *(uint4*)(lds + bwoff[cc]) =
          make_uint4(pk2(f[0 * 4 + cc], f[1 * 4 + cc]), pk2(f[2 * 4 + cc], f[3 * 4 + cc]),
                     pk2(f[4 * 4 + cc], f[5 * 4 + cc]), pk2(f[6 * 4 + cc], f[7 * 4 + cc]));
  };
  auto COMPUTE = [&](int Aoff) {
#pragma unroll
    for (int kk = 0; kk < 2; ++kk) {
      bf16x8 af[4], bf[4];
#pragma unroll
      for (int mi = 0; mi < 4; ++mi)
        af[mi] = *(const bf16x8*)(lds + Aoff + kk * 8192 + aoff[mi]);
#pragma unroll
      for (int ni = 0; ni < 4; ++ni)
        bf[ni] = *(const bf16x8*)(lds + kk * 8192 + boff[ni]);
      __builtin_amdgcn_s_setprio(1);
#pragma unroll
      for (int mi = 0; mi < 4; ++mi)
#pragma unroll
        for (int ni = 0; ni < 4; ++ni)
          acc[mi][ni] = __builtin_amdgcn_mfma_f32_16x16x32_bf16(af[mi], bf[ni], acc[mi][ni], 0, 0, 0);
      __builtin_amdgcn_s_setprio(0);
    }
  };

  // prologue: Bs <- B(0); bQ <- B(1); bP <- B(2); A(0)->buf0; A(1)->buf1
  ISSUE_B(bP, 0);  ISSUE_A(0, 0);
  ISSUE_B(bQ, 1);  ISSUE_A(16384, 1);
  WRITEB(bP);                       // compiler waits exactly on bP=B(0)
  ISSUE_B(bP, 2);
  asm volatile("s_waitcnt vmcnt(20) lgkmcnt(0)" ::: "memory");
  __builtin_amdgcn_s_barrier();

#pragma unroll 1
  for (int kt = 0; kt < NT; kt += 2) {
    // even iter kt: compute A-buf0 + Bs=B(kt); then stage B(kt+1) from bQ
    COMPUTE(0);
    __builtin_amdgcn_s_barrier();
    WRITEB(bQ);                     // bQ = B(kt+1), issued 2 iters ago
    ISSUE_B(bQ, (kt + 3) & NTM);
    ISSUE_A(0, (kt + 2) & NTM);     // refill buf0 with A(kt+2)
    asm volatile("s_waitcnt vmcnt(12) lgkmcnt(0)" ::: "memory");
    __builtin_amdgcn_s_barrier();
    // odd iter kt+1: compute A-buf1 + Bs=B(kt+1); stage B(kt+2) from bP
    COMPUTE(16384);
    __builtin_amdgcn_s_barrier();
    WRITEB(bP);                     // bP = B(kt+2)
    ISSUE_B(bP, (kt + 4) & NTM);
    ISSUE_A(16384, (kt + 3) & NTM); // refill buf1 with A(kt+3)
    asm volatile("s_waitcnt vmcnt(12) lgkmcnt(0)" ::: "memory");
    __builtin_amdgcn_s_barrier();
  }
  asm volatile("s_waitcnt vmcnt(0)" ::: "memory");
  __builtin_amdgcn_s_barrier();

  // ---- epilogue: relu, LDS transpose to H2-image (32KB @ lds+0) -------
  char* img = lds;
#pragma unroll
  for (int mi = 0; mi < 4; ++mi) {
#pragma unroll
    for (int ni = 0; ni < 4; ++ni) {
      const int colL = wc * 64 + ni * 16 + ln15;
      const int basei = (colL >> 6) * 16384 + ((colL >> 3) & 7) * 2048 + (colL & 7) * 2;
#pragma unroll
      for (int j = 0; j < 4; ++j) {
        const int rowL = wr * 64 + mi * 16 + l16 * 4 + j;
        float v = acc[mi][ni][j];
        v = v > 0.f ? v : 0.f;
        *(unsigned short*)(img + basei + rowL * 16) = f2bf(v);
      }
    }
  }
  __syncthreads();
  const char* src = img + tid * 128;
  char* dst = (char*)H2 + (size_t)e * 4194304 +
              (size_t)((n0 >> 6) + (tid >> 7)) * 65536 +
              (size_t)((tid >> 4) & 7) * 8192 +
              (size_t)(m0 + (tid & 15) * 8) * 16;
#pragma unroll
  for (int u = 0; u < 8; ++u)
    *(uint4*)(dst + u * 16) = *(const uint4*)(src + u * 16);
}

// ---------------- GEMM2: out[tok] = (H2[e] @ w2[e]) * gate -------------
#define G2_BX 4
#define G2_BY 8
#define G2_BZ 16
__global__ void __launch_bounds__(256, 3)
gemm2_kernel(const unsigned short* __restrict__ H2, const float* __restrict__ W2,
             const int* __restrict__ s2t, const float* __restrict__ gval,
             float* __restrict__ Out) {
  constexpr int NT = NF / 64;   // 64
  constexpr int NTM = NT - 1;
  __shared__ __align__(16) char lds[49152];

  const int tid = threadIdx.x;
  const int lane = tid & 63, wid = tid >> 6;
  const int wr = wid >> 1, wc = wid & 1;
  const int ln15 = lane & 15, l16 = lane >> 4;

  const int flat = blockIdx.x + G2_BX * (blockIdx.y + G2_BY * blockIdx.z);
  const int xcd = flat & 7, jj = flat >> 3;      // jj 0..63
  const int e  = xcd * 2 + (jj >> 5);
  const int rr = jj & 31;
  const int by = rr >> 2, bx = rr & 3;
  const int m0 = bx * 128, n0 = by * 128;

  const int rb = wid >> 1;
  const int kgw = (wid & 1) * 4;
  const int adst = kgw * 2048 + rb * 1024;
  const char* const aSrc = (const char*)H2 + (size_t)e * 4194304 +
                           (size_t)(m0 + rb * 64 + lane) * 16;

  const int c0 = (tid & 31) * 4;
  const int kq = tid >> 5;
  const float* const bsrc = W2 + (size_t)e * NF * DM + (size_t)(kq * 8) * DM + n0 + c0;
  int bwoff[4];
#pragma unroll
  for (int cc = 0; cc < 4; ++cc) bwoff[cc] = 32768 + kq * 2048 + pcol(c0 + cc) * 16;

  int aoff[4], boff[4];
#pragma unroll
  for (int mi = 0; mi < 4; ++mi)
    aoff[mi] = l16 * 2048 + (wr * 64 + mi * 16 + ln15) * 16;
#pragma unroll
  for (int ni = 0; ni < 4; ++ni)
    boff[ni] = 32768 + l16 * 2048 + pcol(wc * 64 + ni * 16 + ln15) * 16;

  f32x4 acc[4][4];
#pragma unroll
  for (int mi = 0; mi < 4; ++mi)
#pragma unroll
    for (int ni = 0; ni < 4; ++ni) acc[mi][ni] = f32x4{0.f, 0.f, 0.f, 0.f};

  float4 bP[8], bQ[8];

  auto ISSUE_B = [&](float4* br, int kt) {
    const float* bp = bsrc + (size_t)kt * 64 * DM;
#pragma unroll
    for (int r = 0; r < 8; ++r) br[r] = *(const float4*)(bp + (size_t)r * DM);
  };
  auto ISSUE_A = [&](int Aoff, int kt) {
#pragma unroll
    for (int j = 0; j < 4; ++j)
      gload_lds16(aSrc + (size_t)kt * 65536 + (size_t)(kgw + j) * 8192,
                  lds + Aoff + adst + j * 2048);
  };
  auto WRITEB = [&](const float4* br) {
    const float* f = (const float*)br;
#pragma unroll
    for (int cc = 0; cc < 4; ++cc)
      *(uint4*)(lds + bwoff[cc]) =
          make_uint4(pk2(f[0 * 4 + cc], f[1 * 4 + cc]), pk2(f[2 * 4 + cc], f[3 * 4 + cc]),
                     pk2(f[4 * 4 + cc], f[5 * 4 + cc]), pk2(f[6 * 4 + cc], f[7 * 4 + cc]));
  };
  auto COMPUTE = [&](int Aoff) {
#pragma unroll
    for (int kk = 0; kk < 2; ++kk) {
      bf16x8 af[4], bf[4];
#pragma unroll
      for (int mi = 0; mi < 4; ++mi)
        af[mi] = *(const bf16x8*)(lds + Aoff + kk * 8192 + aoff[mi]);
#pragma unroll
      for (int ni = 0; ni < 4; ++ni)
        bf[ni] = *(const bf16x8*)(lds + kk * 8192 + boff[ni]);
      __builtin_amdgcn_s_setprio(1);
#pragma unroll
      for (int mi = 0; mi < 4; ++mi)
#pragma unroll
        for (int ni = 0; ni < 4; ++ni)
          acc[mi][ni] = __builtin_amdgcn_mfma_f32_16x16x32_bf16(af[mi], bf[ni], acc[mi][ni], 0, 0, 0);
      __builtin_amdgcn_s_setprio(0);
    }
  };

  ISSUE_B(bP, 0);  ISSUE_A(0, 0);
  ISSUE_B(bQ, 1);  ISSUE_A(16384, 1);
  WRITEB(bP);
  ISSUE_B(bP, 2);
  asm volatile("s_waitcnt vmcnt(20) lgkmcnt(0)" ::: "memory");
  __builtin_amdgcn_s_barrier();

#pragma unroll 1
  for (int kt = 0; kt < NT; kt += 2) {
    COMPUTE(0);
    __builtin_amdgcn_s_barrier();
    WRITEB(bQ);
    ISSUE_B(bQ, (kt + 3) & NTM);
    ISSUE_A(0, (kt + 2) & NTM);
    asm volatile("s_waitcnt vmcnt(12) lgkmcnt(0)" ::: "memory");
    __builtin_amdgcn_s_barrier();
    COMPUTE(16384);
    __builtin_amdgcn_s_barrier();
    WRITEB(bP);
    ISSUE_B(bP, (kt + 4) & NTM);
    ISSUE_A(16384, (kt + 3) & NTM);
    asm volatile("s_waitcnt vmcnt(12) lgkmcnt(0)" ::: "memory");
    __builtin_amdgcn_s_barrier();
  }
  asm volatile("s_waitcnt vmcnt(0)" ::: "memory");

#pragma unroll
  for (int mi = 0; mi < 4; ++mi) {
#pragma unroll
    for (int ni = 0; ni < 4; ++ni) {
      const int col = n0 + wc * 64 + ni * 16 + ln15;
#pragma unroll
      for (int j = 0; j < 4; ++j) {
        const int row = m0 + wr * 64 + mi * 16 + l16 * 4 + j;
        const int tk = s2t[e * CAP + row];
        if (tk >= 0)
          Out[(size_t)tk * DM + col] = acc[mi][ni][j] * gval[tk];
      }
    }
  }
}

// ----------------------------- launcher --------------------------------
extern "C" void kernel_launch(void* const* d_in, const int* in_sizes, int n_in,
                              void* d_out, int out_size, void* d_ws, size_t ws_size,
                              hipStream_t stream) {
  (void)in_sizes; (void)n_in; (void)ws_size;
  const float* X  = (const float*)d_in[0];
  const float* Wg = (const float*)d_in[1];
  const float* W1 = (const float*)d_in[2];
  const float* W2 = (const float*)d_in[3];
  float* Out = (float*)d_out;

  char* ws = (char*)d_ws;
  int*   s2t  = (int*)ws;                            // 32 KB
  int*   idx  = (int*)(ws + 32768);
  float* gval = (float*)(ws + 65536);
  unsigned short* Xg = (unsigned short*)(ws + 98304);            // 16 MB blocked gathered
  unsigned short* H2 = (unsigned short*)(ws + 98304 + 16777216); // 64 MB blocked

  zero_kernel<<<2048, 256, 0, stream>>>((float4*)Out, out_size / 4);
  gate_kernel<<<S_TOK / 16, 256, 0, stream>>>(X, Wg, idx, gval);
  scan_kernel<<<1, 1024, 0, stream>>>(idx, s2t);
  gather_kernel<<<512, 256, 0, stream>>>(X, s2t, Xg);
  gemm1_kernel<<<dim3(G1_BX, G1_BY, G1_BZ), 256, 0, stream>>>(Xg, W1, H2);
  gemm2_kernel<<<dim3(G2_BX, G2_BY, G2_BZ), 256, 0, stream>>>(H2, W2, s2t, gval, Out);
}

// Round 13
// 305.978 us; speedup vs baseline: 3.2708x; 3.2708x over previous
//
#include <hip/hip_runtime.h>
#include <cstdint>
#include <cstddef>

#define S_TOK 8192
#define DM    1024
#define NE    16
#define NF    4096
#define CAP   512

typedef __attribute__((ext_vector_type(8))) short bf16x8;
typedef __attribute__((ext_vector_type(4))) float f32x4;

__device__ __forceinline__ unsigned short f2bf(float f) {
  __bf16 b = (__bf16)f;
  return __builtin_bit_cast(unsigned short, b);
}
__device__ __forceinline__ unsigned pk2(float a, float b) {
  return (unsigned)f2bf(a) | ((unsigned)f2bf(b) << 16);
}
// bank-spread for the B [kg][col][16B] LDS layout
__device__ __forceinline__ int pcol(int c) { return c ^ ((c >> 3) & 7); }

__device__ __forceinline__ void gload_lds16(const void* g, void* l) {
  __builtin_amdgcn_global_load_lds(
      (const __attribute__((address_space(1))) void*)g,
      (__attribute__((address_space(3))) void*)l, 16, 0, 0);
}

// ---------------- fast zero of d_out ------------------------------------
__global__ void __launch_bounds__(256)
zero_kernel(float4* __restrict__ Out, int n4) {
  const int stride = gridDim.x * 256;
  for (int i = blockIdx.x * 256 + threadIdx.x; i < n4; i += stride)
    Out[i] = float4{0.f, 0.f, 0.f, 0.f};
}

// ---------------- gating: logits fp32, softmax, argmax -----------------
__global__ void __launch_bounds__(256)
gate_kernel(const float* __restrict__ X, const float* __restrict__ Wg,
            int* __restrict__ idx, float* __restrict__ gval) {
  const int tid  = threadIdx.x;
  const int lane = tid & 63;
  const int wid  = tid >> 6;
  const int e = lane & 15, q = lane >> 4;
  const int t0 = blockIdx.x * 16 + wid * 4;
  const int mbase = q * 256;

  const float* xp0 = X + (size_t)(t0 + 0) * DM + mbase;
  const float* xp1 = X + (size_t)(t0 + 1) * DM + mbase;
  const float* xp2 = X + (size_t)(t0 + 2) * DM + mbase;
  const float* xp3 = X + (size_t)(t0 + 3) * DM + mbase;
  const float* wp  = Wg + (size_t)mbase * NE + e;

  float a0 = 0.f, a1 = 0.f, a2 = 0.f, a3 = 0.f;
#pragma unroll 4
  for (int i = 0; i < 64; ++i) {
    float4 x0 = *(const float4*)(xp0 + i * 4);
    float4 x1 = *(const float4*)(xp1 + i * 4);
    float4 x2 = *(const float4*)(xp2 + i * 4);
    float4 x3 = *(const float4*)(xp3 + i * 4);
    float w0 = wp[(i * 4 + 0) * NE];
    float w1 = wp[(i * 4 + 1) * NE];
    float w2 = wp[(i * 4 + 2) * NE];
    float w3 = wp[(i * 4 + 3) * NE];
    a0 = fmaf(x0.x, w0, fmaf(x0.y, w1, fmaf(x0.z, w2, fmaf(x0.w, w3, a0))));
    a1 = fmaf(x1.x, w0, fmaf(x1.y, w1, fmaf(x1.z, w2, fmaf(x1.w, w3, a1))));
    a2 = fmaf(x2.x, w0, fmaf(x2.y, w1, fmaf(x2.z, w2, fmaf(x2.w, w3, a2))));
    a3 = fmaf(x3.x, w0, fmaf(x3.y, w1, fmaf(x3.z, w2, fmaf(x3.w, w3, a3))));
  }
#pragma unroll
  for (int s = 16; s < 64; s <<= 1) {
    a0 += __shfl_xor(a0, s, 64);
    a1 += __shfl_xor(a1, s, 64);
    a2 += __shfl_xor(a2, s, 64);
    a3 += __shfl_xor(a3, s, 64);
  }
  float l = (q == 0) ? a0 : (q == 1) ? a1 : (q == 2) ? a2 : a3;
  float bv = l; int bi = e;
#pragma unroll
  for (int s = 1; s < 16; s <<= 1) {
    float ov = __shfl_xor(bv, s, 16);
    int   oi = __shfl_xor(bi, s, 16);
    if (ov > bv || (ov == bv && oi < bi)) { bv = ov; bi = oi; }
  }
  float p  = expf(l - bv);
  float sm = p;
#pragma unroll
  for (int s = 1; s < 16; s <<= 1) sm += __shfl_xor(sm, s, 16);
  if (e == 0) {
    idx[t0 + q]  = bi;
    gval[t0 + q] = 1.0f / sm;
  }
}

// ---------------- routing scan: capacity-limited slot assignment -------
__global__ void __launch_bounds__(1024)
scan_kernel(const int* __restrict__ idx, int* __restrict__ s2t) {
  const int tid = threadIdx.x;
#pragma unroll
  for (int k = 0; k < 8; ++k) s2t[tid + k * 1024] = -1;
  __shared__ int base[16];
  __shared__ int wavecnt[16][16];
  if (tid < 16) base[tid] = 0;
  __syncthreads();
  const int wid = tid >> 6, lane = tid & 63;
  const unsigned long long ltmask = (1ull << lane) - 1ull;
  for (int c = 0; c < 8; ++c) {
    const int t = c * 1024 + tid;
    const int e = idx[t];
    int rank = 0;
#pragma unroll
    for (int ee = 0; ee < 16; ++ee) {
      unsigned long long m = __ballot(e == ee);
      if (lane == 0) wavecnt[wid][ee] = __popcll(m);
      if (ee == e) rank = __popcll(m & ltmask);
    }
    __syncthreads();
    if (tid < 16) {
      int s = base[tid];
#pragma unroll
      for (int w = 0; w < 16; ++w) { int cc = wavecnt[w][tid]; wavecnt[w][tid] = s; s += cc; }
      base[tid] = s;
    }
    __syncthreads();
    const int loc = wavecnt[wid][e] + rank;
    if (loc < CAP) s2t[e * CAP + loc] = t;
    __syncthreads();
  }
}

// ---------------- gather + cvt: X fp32 rows -> blocked gathered bf16 ----
// Xg layout: [e][kt(16)][kg(8)][slot(512)][16B]; 1 MB/expert, 16 MB.
__global__ void __launch_bounds__(256)
gather_kernel(const float* __restrict__ X, const int* __restrict__ s2t,
              unsigned short* __restrict__ Xg) {
  const int tid = threadIdx.x;
  const int d  = tid & 127;           // 8 floats per thread
  const int sl = tid >> 7;            // 0..1
  const int s0 = blockIdx.x * 16;     // 16 slots per block
#pragma unroll 2
  for (int p = 0; p < 8; ++p) {
    const int s = s0 + p * 2 + sl;
    const int tok = s2t[s];
    uint4 w;
    if (tok >= 0) {
      const float* xp = X + (size_t)tok * DM + d * 8;
      float4 v0 = *(const float4*)xp;
      float4 v1 = *(const float4*)(xp + 4);
      w = make_uint4(pk2(v0.x, v0.y), pk2(v0.z, v0.w),
                     pk2(v1.x, v1.y), pk2(v1.z, v1.w));
    } else {
      w = make_uint4(0u, 0u, 0u, 0u);
    }
    char* dst = (char*)Xg + (size_t)(s >> 9) * 1048576 +
                (size_t)(d >> 3) * 65536 + (size_t)(d & 7) * 8192 +
                (size_t)(s & 511) * 16;
    *(uint4*)dst = w;
  }
}

// H2 layout: [e][kt(64)][kg(8)][row(512)][8 bf16]; per-expert 4 MB.

// ---------------- GEMM1 (R13): 256x128 tile, 8 waves, 80 KB LDS --------
// A: double-buffered 2x32 KB via gload_lds (@0, @32768); B: single 16 KB
// (@65536) + reg PING-PONG depth-2 (bP/bQ, x2 unroll) -> WRITEB consumes
// loads issued 2 iters back. 80 KB -> 2 blocks/CU co-resident: inter-
// block overlap fills barrier stalls (m97 regime). Counted vmcnt(12).
#define G1_BX 2
#define G1_BY 32
#define G1_BZ 16
__global__ void __launch_bounds__(512, 2)
gemm1_kernel(const unsigned short* __restrict__ Xg, const float* __restrict__ W1,
             unsigned short* __restrict__ H2) {
  constexpr int NT = DM / 64;   // 16
  __shared__ __align__(16) char lds[81920];

  const int tid = threadIdx.x;
  const int lane = tid & 63, wid = tid >> 6;
  const int wr = wid >> 1, wc = wid & 1;
  const int ln15 = lane & 15, l16 = lane >> 4;

  const int flat = blockIdx.x + G1_BX * (blockIdx.y + G1_BY * blockIdx.z);
  const int xcd = flat & 7, jj = flat >> 3;      // jj 0..127
  const int e  = xcd * 2 + (jj >> 6);
  const int rr = jj & 63;
  const int by = rr >> 1, bx = rr & 1;
  const int m0 = bx * 256, n0 = by * 128;

  // A: wave covers rows rb*64+lane (rb = wid>>1), kg = (wid&1)*4+j
  const int rb = wid >> 1;
  const int kgw = (wid & 1) * 4;
  const int adst = kgw * 4096 + rb * 1024;
  const char* const aSrc = (const char*)Xg + (size_t)e * 1048576 +
                           (size_t)(m0 + rb * 64 + lane) * 16;

  // B: cols c0..c0+3, k-rows 4*kq..4*kq+3
  const int c0 = (tid & 31) * 4;
  const int kq = tid >> 5;
  const float* const bsrc = W1 + (size_t)e * DM * NF + (size_t)(kq * 4) * NF + n0 + c0;
  const int kgb = kq >> 1, hb = kq & 1;
  int bwoff[4];
#pragma unroll
  for (int cc = 0; cc < 4; ++cc)
    bwoff[cc] = 65536 + kgb * 2048 + pcol(c0 + cc) * 16 + hb * 8;

  int aoff[4], boff[4];
#pragma unroll
  for (int mi = 0; mi < 4; ++mi) aoff[mi] = l16 * 4096 + (wr * 64 + mi * 16 + ln15) * 16;
#pragma unroll
  for (int ni = 0; ni < 4; ++ni)
    boff[ni] = 65536 + l16 * 2048 + pcol(wc * 64 + ni * 16 + ln15) * 16;

  f32x4 acc[4][4];
#pragma unroll
  for (int mi = 0; mi < 4; ++mi)
#pragma unroll
    for (int ni = 0; ni < 4; ++ni) acc[mi][ni] = f32x4{0.f, 0.f, 0.f, 0.f};

  float4 bP[4], bQ[4];

  auto ISSUE_B = [&](float4* br, int kt) {
    const float* bp = bsrc + (size_t)kt * 64 * NF;
#pragma unroll
    for (int r = 0; r < 4; ++r) br[r] = *(const float4*)(bp + (size_t)r * NF);
  };
  auto ISSUE_A = [&](int Aoff, int kt) {
#pragma unroll
    for (int j = 0; j < 4; ++j)
      gload_lds16(aSrc + (size_t)kt * 65536 + (size_t)(kgw + j) * 8192,
                  lds + Aoff + adst + j * 4096);
  };
  auto WRITEB = [&](const float4* br) {
    const float* f = (const float*)br;
#pragma unroll
    for (int cc = 0; cc < 4; ++cc)
      *(uint2*)(lds + bwoff[cc]) =
          make_uint2(pk2(f[0 + cc], f[4 + cc]), pk2(f[8 + cc], f[12 + cc]));
  };
  auto COMPUTE = [&](int Aoff) {
#pragma unroll
    for (int kk = 0; kk < 2; ++kk) {
      bf16x8 af[4], bf[4];
#pragma unroll
      for (int mi = 0; mi < 4; ++mi)
        af[mi] = *(const bf16x8*)(lds + Aoff + kk * 16384 + aoff[mi]);
#pragma unroll
      for (int ni = 0; ni < 4; ++ni)
        bf[ni] = *(const bf16x8*)(lds + kk * 8192 + boff[ni]);
      __builtin_amdgcn_s_setprio(1);
#pragma unroll
      for (int mi = 0; mi < 4; ++mi)
#pragma unroll
        for (int ni = 0; ni < 4; ++ni)
          acc[mi][ni] = __builtin_amdgcn_mfma_f32_16x16x32_bf16(af[mi], bf[ni], acc[mi][ni], 0, 0, 0);
      __builtin_amdgcn_s_setprio(0);
    }
  };

  // prologue: Bs <- B(0); bQ <- B(1); bP <- B(2); A(0)->buf0; A(1)->buf1
  ISSUE_B(bP, 0); ISSUE_A(0, 0);
  ISSUE_B(bQ, 1); ISSUE_A(32768, 1);
  WRITEB(bP);                       // compiler inserts exact wait on bP
  ISSUE_B(bP, 2);
  asm volatile("s_waitcnt vmcnt(12) lgkmcnt(0)" ::: "memory");
  __builtin_amdgcn_s_barrier();

#pragma unroll 1
  for (int kt = 0; kt < NT; kt += 2) {
    // even iter kt: compute { A(kt) in buf0, B(kt) in Bs }
    COMPUTE(0);
    __builtin_amdgcn_s_barrier();   // all waves done reading buf0 + Bs
    WRITEB(bQ);                     // Bs <- B(kt+1) (regs from 2 iters back)
    ISSUE_B(bQ, (kt + 3 < NT) ? kt + 3 : NT - 1);
    ISSUE_A(0, (kt + 2 < NT) ? kt + 2 : NT - 1);   // buf0 <- A(kt+2)
    asm volatile("s_waitcnt vmcnt(12) lgkmcnt(0)" ::: "memory");
    __builtin_amdgcn_s_barrier();   // A(kt+1) landed; B(kt+1) visible
    // odd iter kt+1: compute { A(kt+1) in buf1, B(kt+1) in Bs }
    COMPUTE(32768);
    __builtin_amdgcn_s_barrier();
    WRITEB(bP);                     // Bs <- B(kt+2)
    ISSUE_B(bP, (kt + 4 < NT) ? kt + 4 : NT - 1);
    ISSUE_A(32768, (kt + 3 < NT) ? kt + 3 : NT - 1);
    asm volatile("s_waitcnt vmcnt(12) lgkmcnt(0)" ::: "memory");
    __builtin_amdgcn_s_barrier();
  }
  asm volatile("s_waitcnt vmcnt(0)" ::: "memory");
  __builtin_amdgcn_s_barrier();

  // ---- epilogue: relu, LDS transpose to H2-image (64KB @ lds+0) -------
  char* img = lds;
#pragma unroll
  for (int mi = 0; mi < 4; ++mi) {
#pragma unroll
    for (int ni = 0; ni < 4; ++ni) {
      const int colL = wc * 64 + ni * 16 + ln15;
      const int basei = (colL >> 6) * 32768 + ((colL >> 3) & 7) * 4096 + (colL & 7) * 2;
#pragma unroll
      for (int j = 0; j < 4; ++j) {
        const int rowL = wr * 64 + mi * 16 + l16 * 4 + j;
        float v = acc[mi][ni][j];
        v = v > 0.f ? v : 0.f;
        *(unsigned short*)(img + basei + rowL * 16) = f2bf(v);
      }
    }
  }
  __syncthreads();
  const char* src = img + tid * 128;
  char* dst = (char*)H2 + (size_t)e * 4194304 +
              (size_t)((n0 >> 6) + (tid >> 8)) * 65536 +
              (size_t)((tid >> 5) & 7) * 8192 +
              (size_t)(m0 + (tid & 31) * 8) * 16;
#pragma unroll
  for (int u = 0; u < 8; ++u)
    *(uint4*)(dst + u * 16) = *(const uint4*)(src + u * 16);
}

// ---------------- GEMM2 (R8-proven): out[tok] = (H2[e] @ w2[e]) * gate --
#define G2_BX 2
#define G2_BY 8
#define G2_BZ 16
__global__ void __launch_bounds__(512, 2)
gemm2_kernel(const unsigned short* __restrict__ H2, const float* __restrict__ W2,
             const int* __restrict__ s2t, const float* __restrict__ gval,
             float* __restrict__ Out) {
  constexpr int NT = NF / 64;  // 64
  __shared__ __align__(16) char lds[131072];

  const int tid = threadIdx.x;
  const int lane = tid & 63, wid = tid >> 6;
  const int wr = wid >> 1, wc = wid & 1;
  const int ln15 = lane & 15, l16 = lane >> 4;

  const int flat = blockIdx.x + G2_BX * (blockIdx.y + G2_BY * blockIdx.z);
  const int xcd = flat & 7, jj = flat >> 3;      // jj 0..31
  const int e  = xcd * 2 + (jj >> 4);
  const int rr = jj & 15;
  const int by = rr >> 1, bx = rr & 1;
  const int m0 = bx * 256, n0 = by * 128;

  char* const Bb0 = lds + 98304;
  char* const Bb1 = lds + 98304 + 16384;

  const int rb = wid >> 1;
  const int kgw = (wid & 1) * 4;
  const int adst = kgw * 4096 + rb * 1024;
  const char* const Hex = (const char*)H2 + (size_t)e * 4194304 +
                          (size_t)(m0 + rb * 64 + lane) * 16;

  const int c0 = (tid & 31) * 4;
  const int kq = tid >> 5;
  const float* const bsrc = W2 + (size_t)e * NF * DM + (size_t)(kq * 4) * DM + n0 + c0;
  const int kgb = kq >> 1, hb = kq & 1;
  int bwoff[4];
#pragma unroll
  for (int cc = 0; cc < 4; ++cc) bwoff[cc] = kgb * 2048 + pcol(c0 + cc) * 16 + hb * 8;

  int aoff[4], boff[4];
#pragma unroll
  for (int mi = 0; mi < 4; ++mi) aoff[mi] = l16 * 4096 + (wr * 64 + mi * 16 + ln15) * 16;
#pragma unroll
  for (int ni = 0; ni < 4; ++ni) boff[ni] = l16 * 2048 + pcol(wc * 64 + ni * 16 + ln15) * 16;

  f32x4 acc[4][4];
#pragma unroll
  for (int mi = 0; mi < 4; ++mi)
#pragma unroll
    for (int ni = 0; ni < 4; ++ni) acc[mi][ni] = f32x4{0.f, 0.f, 0.f, 0.f};

  float4 breg[4];

  auto ISSUE_B = [&](int kt) {
    const float* bp = bsrc + (size_t)kt * 64 * DM;
#pragma unroll
    for (int r = 0; r < 4; ++r) breg[r] = *(const float4*)(bp + (size_t)r * DM);
  };
  auto ISSUE_A = [&](int Aoff, int kt) {
#pragma unroll
    for (int j = 0; j < 4; ++j)
      gload_lds16(Hex + (size_t)kt * 65536 + (size_t)(kgw + j) * 8192,
                  lds + Aoff + adst + j * 4096);
  };
  auto WRITEB = [&](char* Bbuf) {
    const float* f = (const float*)breg;
#pragma unroll
    for (int cc = 0; cc < 4; ++cc)
      *(uint2*)(Bbuf + bwoff[cc]) =
          make_uint2(pk2(f[0 + cc], f[4 + cc]), pk2(f[8 + cc], f[12 + cc]));
  };
  auto COMPUTE = [&](int Aoff, const char* Bbuf) {
#pragma unroll
    for (int kk = 0; kk < 2; ++kk) {
      bf16x8 af[4], bf[4];
#pragma unroll
      for (int mi = 0; mi < 4; ++mi)
        af[mi] = *(const bf16x8*)(lds + Aoff + kk * 16384 + aoff[mi]);
#pragma unroll
      for (int ni = 0; ni < 4; ++ni)
        bf[ni] = *(const bf16x8*)(Bbuf + kk * 8192 + boff[ni]);
#pragma unroll
      for (int mi = 0; mi < 4; ++mi)
#pragma unroll
        for (int ni = 0; ni < 4; ++ni)
          acc[mi][ni] = __builtin_amdgcn_mfma_f32_16x16x32_bf16(af[mi], bf[ni], acc[mi][ni], 0, 0, 0);
    }
  };

  ISSUE_B(0); ISSUE_A(0, 0);
  WRITEB(Bb0);
  ISSUE_B(1); ISSUE_A(32768, 1);
  asm volatile("s_waitcnt vmcnt(8) lgkmcnt(0)" ::: "memory");
  __builtin_amdgcn_s_barrier();

  int aCur = 0, aNxt = 32768, aNx2 = 65536;
  for (int kt = 0; kt < NT; ++kt) {
    WRITEB((kt & 1) ? Bb0 : Bb1);
    const int tl = (kt + 2 < NT) ? kt + 2 : NT - 1;
    ISSUE_B(tl);
    ISSUE_A(aNx2, tl);
    COMPUTE(aCur, (kt & 1) ? Bb1 : Bb0);
    asm volatile("s_waitcnt vmcnt(8) lgkmcnt(0)" ::: "memory");
    __builtin_amdgcn_s_barrier();
    const int t = aCur; aCur = aNxt; aNxt = aNx2; aNx2 = t;
  }
  asm volatile("s_waitcnt vmcnt(0)" ::: "memory");

#pragma unroll
  for (int mi = 0; mi < 4; ++mi) {
#pragma unroll
    for (int ni = 0; ni < 4; ++ni) {
      const int col = n0 + wc * 64 + ni * 16 + ln15;
#pragma unroll
      for (int j = 0; j < 4; ++j) {
        const int row = m0 + wr * 64 + mi * 16 + l16 * 4 + j;
        const int tk = s2t[e * CAP + row];
        if (tk >= 0)
          Out[(size_t)tk * DM + col] = acc[mi][ni][j] * gval[tk];
      }
    }
  }
}

// ----------------------------- launcher --------------------------------
extern "C" void kernel_launch(void* const* d_in, const int* in_sizes, int n_in,
                              void* d_out, int out_size, void* d_ws, size_t ws_size,
                              hipStream_t stream) {
  (void)in_sizes; (void)n_in; (void)ws_size;
  const float* X  = (const float*)d_in[0];
  const float* Wg = (const float*)d_in[1];
  const float* W1 = (const float*)d_in[2];
  const float* W2 = (const float*)d_in[3];
  float* Out = (float*)d_out;

  char* ws = (char*)d_ws;
  int*   s2t  = (int*)ws;                            // 32 KB
  int*   idx  = (int*)(ws + 32768);
  float* gval = (float*)(ws + 65536);
  unsigned short* Xg = (unsigned short*)(ws + 98304);            // 16 MB blocked gathered
  unsigned short* H2 = (unsigned short*)(ws + 98304 + 16777216); // 64 MB blocked

  zero_kernel<<<2048, 256, 0, stream>>>((float4*)Out, out_size / 4);
  gate_kernel<<<S_TOK / 16, 256, 0, stream>>>(X, Wg, idx, gval);
  scan_kernel<<<1, 1024, 0, stream>>>(idx, s2t);
  gather_kernel<<<512, 256, 0, stream>>>(X, s2t, Xg);
  gemm1_kernel<<<dim3(G1_BX, G1_BY, G1_BZ), 512, 0, stream>>>(Xg, W1, H2);
  gemm2_kernel<<<dim3(G2_BX, G2_BY, G2_BZ), 512, 0, stream>>>(H2, W2, s2t, gval, Out);
}

// Round 14
// 282.444 us; speedup vs baseline: 3.5433x; 1.0833x over previous
//
#include <hip/hip_runtime.h>
#include <cstdint>
#include <cstddef>

#define S_TOK 8192
#define DM    1024
#define NE    16
#define NF    4096
#define CAP   512

typedef __attribute__((ext_vector_type(8))) short bf16x8;
typedef __attribute__((ext_vector_type(4))) float f32x4;

__device__ __forceinline__ unsigned short f2bf(float f) {
  __bf16 b = (__bf16)f;
  return __builtin_bit_cast(unsigned short, b);
}
__device__ __forceinline__ unsigned pk2(float a, float b) {
  return (unsigned)f2bf(a) | ((unsigned)f2bf(b) << 16);
}
// bank-spread for the B [kg][col][16B] LDS layout
__device__ __forceinline__ int pcol(int c) { return c ^ ((c >> 3) & 7); }

__device__ __forceinline__ void gload_lds16(const void* g, void* l) {
  __builtin_amdgcn_global_load_lds(
      (const __attribute__((address_space(1))) void*)g,
      (__attribute__((address_space(3))) void*)l, 16, 0, 0);
}

// ---------------- fast zero of d_out ------------------------------------
__global__ void __launch_bounds__(256)
zero_kernel(float4* __restrict__ Out, int n4) {
  const int stride = gridDim.x * 256;
  for (int i = blockIdx.x * 256 + threadIdx.x; i < n4; i += stride)
    Out[i] = float4{0.f, 0.f, 0.f, 0.f};
}

// ---------------- gating: logits fp32, softmax, argmax -----------------
__global__ void __launch_bounds__(256)
gate_kernel(const float* __restrict__ X, const float* __restrict__ Wg,
            int* __restrict__ idx, float* __restrict__ gval) {
  const int tid  = threadIdx.x;
  const int lane = tid & 63;
  const int wid  = tid >> 6;
  const int e = lane & 15, q = lane >> 4;
  const int t0 = blockIdx.x * 16 + wid * 4;
  const int mbase = q * 256;

  const float* xp0 = X + (size_t)(t0 + 0) * DM + mbase;
  const float* xp1 = X + (size_t)(t0 + 1) * DM + mbase;
  const float* xp2 = X + (size_t)(t0 + 2) * DM + mbase;
  const float* xp3 = X + (size_t)(t0 + 3) * DM + mbase;
  const float* wp  = Wg + (size_t)mbase * NE + e;

  float a0 = 0.f, a1 = 0.f, a2 = 0.f, a3 = 0.f;
#pragma unroll 4
  for (int i = 0; i < 64; ++i) {
    float4 x0 = *(const float4*)(xp0 + i * 4);
    float4 x1 = *(const float4*)(xp1 + i * 4);
    float4 x2 = *(const float4*)(xp2 + i * 4);
    float4 x3 = *(const float4*)(xp3 + i * 4);
    float w0 = wp[(i * 4 + 0) * NE];
    float w1 = wp[(i * 4 + 1) * NE];
    float w2 = wp[(i * 4 + 2) * NE];
    float w3 = wp[(i * 4 + 3) * NE];
    a0 = fmaf(x0.x, w0, fmaf(x0.y, w1, fmaf(x0.z, w2, fmaf(x0.w, w3, a0))));
    a1 = fmaf(x1.x, w0, fmaf(x1.y, w1, fmaf(x1.z, w2, fmaf(x1.w, w3, a1))));
    a2 = fmaf(x2.x, w0, fmaf(x2.y, w1, fmaf(x2.z, w2, fmaf(x2.w, w3, a2))));
    a3 = fmaf(x3.x, w0, fmaf(x3.y, w1, fmaf(x3.z, w2, fmaf(x3.w, w3, a3))));
  }
#pragma unroll
  for (int s = 16; s < 64; s <<= 1) {
    a0 += __shfl_xor(a0, s, 64);
    a1 += __shfl_xor(a1, s, 64);
    a2 += __shfl_xor(a2, s, 64);
    a3 += __shfl_xor(a3, s, 64);
  }
  float l = (q == 0) ? a0 : (q == 1) ? a1 : (q == 2) ? a2 : a3;
  float bv = l; int bi = e;
#pragma unroll
  for (int s = 1; s < 16; s <<= 1) {
    float ov = __shfl_xor(bv, s, 16);
    int   oi = __shfl_xor(bi, s, 16);
    if (ov > bv || (ov == bv && oi < bi)) { bv = ov; bi = oi; }
  }
  float p  = expf(l - bv);
  float sm = p;
#pragma unroll
  for (int s = 1; s < 16; s <<= 1) sm += __shfl_xor(sm, s, 16);
  if (e == 0) {
    idx[t0 + q]  = bi;
    gval[t0 + q] = 1.0f / sm;
  }
}

// ---------------- routing scan: capacity-limited slot assignment -------
__global__ void __launch_bounds__(1024)
scan_kernel(const int* __restrict__ idx, int* __restrict__ s2t) {
  const int tid = threadIdx.x;
#pragma unroll
  for (int k = 0; k < 8; ++k) s2t[tid + k * 1024] = -1;
  __shared__ int base[16];
  __shared__ int wavecnt[16][16];
  if (tid < 16) base[tid] = 0;
  __syncthreads();
  const int wid = tid >> 6, lane = tid & 63;
  const unsigned long long ltmask = (1ull << lane) - 1ull;
  for (int c = 0; c < 8; ++c) {
    const int t = c * 1024 + tid;
    const int e = idx[t];
    int rank = 0;
#pragma unroll
    for (int ee = 0; ee < 16; ++ee) {
      unsigned long long m = __ballot(e == ee);
      if (lane == 0) wavecnt[wid][ee] = __popcll(m);
      if (ee == e) rank = __popcll(m & ltmask);
    }
    __syncthreads();
    if (tid < 16) {
      int s = base[tid];
#pragma unroll
      for (int w = 0; w < 16; ++w) { int cc = wavecnt[w][tid]; wavecnt[w][tid] = s; s += cc; }
      base[tid] = s;
    }
    __syncthreads();
    const int loc = wavecnt[wid][e] + rank;
    if (loc < CAP) s2t[e * CAP + loc] = t;
    __syncthreads();
  }
}

// ---------------- gather + cvt: X fp32 rows -> blocked gathered bf16 ----
// Xg layout: [e][kt(16)][kg(8)][slot(512)][16B]; 1 MB/expert, 16 MB.
__global__ void __launch_bounds__(256)
gather_kernel(const float* __restrict__ X, const int* __restrict__ s2t,
              unsigned short* __restrict__ Xg) {
  const int tid = threadIdx.x;
  const int d  = tid & 127;           // 8 floats per thread
  const int sl = tid >> 7;            // 0..1
  const int s0 = blockIdx.x * 16;     // 16 slots per block
#pragma unroll 2
  for (int p = 0; p < 8; ++p) {
    const int s = s0 + p * 2 + sl;
    const int tok = s2t[s];
    uint4 w;
    if (tok >= 0) {
      const float* xp = X + (size_t)tok * DM + d * 8;
      float4 v0 = *(const float4*)xp;
      float4 v1 = *(const float4*)(xp + 4);
      w = make_uint4(pk2(v0.x, v0.y), pk2(v0.z, v0.w),
                     pk2(v1.x, v1.y), pk2(v1.z, v1.w));
    } else {
      w = make_uint4(0u, 0u, 0u, 0u);
    }
    char* dst = (char*)Xg + (size_t)(s >> 9) * 1048576 +
                (size_t)(d >> 3) * 65536 + (size_t)(d & 7) * 8192 +
                (size_t)(s & 511) * 16;
    *(uint4*)dst = w;
  }
}

// H2 layout: [e][kt(64)][kg(8)][row(512)][8 bf16]; per-expert 4 MB.

// =======================================================================
// GEMM skeleton (R8-proven): 256(M)x128(N) tile, BK=64, 512 thr (8 waves,
// 4Mx2N). A: triple-buffered LDS via global_load_lds (depth-2 prefetch).
// B: double-buffered LDS, reg-staged fp32->bf16 (loads 1 iter ahead).
// One raw s_barrier per iter with COUNTED s_waitcnt vmcnt(8).
// R14: gemm1 becomes PERSISTENT -- 256 blocks (1/CU, one dispatch round),
// each looping over 4 N-strips for its fixed (e,bx): 64 K-iters/block
// total, same amortization regime as gemm2 (which measured ~690 TF).
// LDS: A 3x32KB @0, B 2x16KB @98304 = 128 KB.
// =======================================================================

// ---------------- GEMM1: H2[e] = relu(Xg[e] @ w1[e]) -------------------
#define G1_BX 2
#define G1_BY 8
#define G1_BZ 16
__global__ void __launch_bounds__(512, 2)
gemm1_kernel(const unsigned short* __restrict__ Xg, const float* __restrict__ W1,
             unsigned short* __restrict__ H2) {
  constexpr int NT = DM / 64;  // 16
  __shared__ __align__(16) char lds[131072];

  const int tid = threadIdx.x;
  const int lane = tid & 63, wid = tid >> 6;
  const int wr = wid >> 1, wc = wid & 1;
  const int ln15 = lane & 15, l16 = lane >> 4;

  const int flat = blockIdx.x + G1_BX * (blockIdx.y + G1_BY * blockIdx.z);
  const int xcd = flat & 7, jj = flat >> 3;      // jj 0..31
  const int e  = xcd * 2 + (jj >> 4);
  const int rr = jj & 15;
  const int byG = rr >> 1, bx = rr & 1;
  const int m0 = bx * 256;

  char* const Bb0 = lds + 98304;
  char* const Bb1 = lds + 98304 + 16384;

  // A: constant across strips; wave covers rows rb*64+lane, kg=(wid&1)*4+j
  const int rb = wid >> 1;
  const int kgw = (wid & 1) * 4;
  const int adst = kgw * 4096 + rb * 1024;
  const char* const aSrc = (const char*)Xg + (size_t)e * 1048576 +
                           (size_t)(m0 + rb * 64 + lane) * 16;

  // B: cols c0..c0+3 (plus n0 per strip), k-rows 4*kq..4*kq+3
  const int c0 = (tid & 31) * 4;
  const int kq = tid >> 5;
  const float* const bsrc0 = W1 + (size_t)e * DM * NF + (size_t)(kq * 4) * NF + c0;
  const int kgb = kq >> 1, hb = kq & 1;
  int bwoff[4];
#pragma unroll
  for (int cc = 0; cc < 4; ++cc) bwoff[cc] = kgb * 2048 + pcol(c0 + cc) * 16 + hb * 8;

  int aoff[4], boff[4];
#pragma unroll
  for (int mi = 0; mi < 4; ++mi) aoff[mi] = l16 * 4096 + (wr * 64 + mi * 16 + ln15) * 16;
#pragma unroll
  for (int ni = 0; ni < 4; ++ni) boff[ni] = l16 * 2048 + pcol(wc * 64 + ni * 16 + ln15) * 16;

  f32x4 acc[4][4];
  float4 breg[4];

#pragma unroll 1
  for (int s = 0; s < 4; ++s) {
    const int n0 = (byG * 4 + s) * 128;
    const float* const bsrc = bsrc0 + n0;

#pragma unroll
    for (int mi = 0; mi < 4; ++mi)
#pragma unroll
      for (int ni = 0; ni < 4; ++ni) acc[mi][ni] = f32x4{0.f, 0.f, 0.f, 0.f};

    auto ISSUE_B = [&](int kt) {
      const float* bp = bsrc + (size_t)kt * 64 * NF;
#pragma unroll
      for (int r = 0; r < 4; ++r) breg[r] = *(const float4*)(bp + (size_t)r * NF);
    };
    auto ISSUE_A = [&](int Aoff, int kt) {
#pragma unroll
      for (int j = 0; j < 4; ++j)
        gload_lds16(aSrc + (size_t)kt * 65536 + (size_t)(kgw + j) * 8192,
                    lds + Aoff + adst + j * 4096);
    };
    auto WRITEB = [&](char* Bbuf) {
      const float* f = (const float*)breg;
#pragma unroll
      for (int cc = 0; cc < 4; ++cc)
        *(uint2*)(Bbuf + bwoff[cc]) =
            make_uint2(pk2(f[0 + cc], f[4 + cc]), pk2(f[8 + cc], f[12 + cc]));
    };
    auto COMPUTE = [&](int Aoff, const char* Bbuf) {
#pragma unroll
      for (int kk = 0; kk < 2; ++kk) {
        bf16x8 af[4], bf[4];
#pragma unroll
        for (int mi = 0; mi < 4; ++mi)
          af[mi] = *(const bf16x8*)(lds + Aoff + kk * 16384 + aoff[mi]);
#pragma unroll
        for (int ni = 0; ni < 4; ++ni)
          bf[ni] = *(const bf16x8*)(Bbuf + kk * 8192 + boff[ni]);
#pragma unroll
        for (int mi = 0; mi < 4; ++mi)
#pragma unroll
          for (int ni = 0; ni < 4; ++ni)
            acc[mi][ni] = __builtin_amdgcn_mfma_f32_16x16x32_bf16(af[mi], bf[ni], acc[mi][ni], 0, 0, 0);
      }
    };

    // prologue (R8)
    ISSUE_B(0); ISSUE_A(0, 0);
    WRITEB(Bb0);
    ISSUE_B(1); ISSUE_A(32768, 1);
    asm volatile("s_waitcnt vmcnt(8) lgkmcnt(0)" ::: "memory");
    __builtin_amdgcn_s_barrier();

    int aCur = 0, aNxt = 32768, aNx2 = 65536;
#pragma unroll 1
    for (int kt = 0; kt < NT; ++kt) {
      WRITEB((kt & 1) ? Bb0 : Bb1);
      const int tl = (kt + 2 < NT) ? kt + 2 : NT - 1;
      ISSUE_B(tl);
      ISSUE_A(aNx2, tl);
      COMPUTE(aCur, (kt & 1) ? Bb1 : Bb0);
      asm volatile("s_waitcnt vmcnt(8) lgkmcnt(0)" ::: "memory");
      __builtin_amdgcn_s_barrier();
      const int t = aCur; aCur = aNxt; aNxt = aNx2; aNx2 = t;
    }
    asm volatile("s_waitcnt vmcnt(0)" ::: "memory");
    __builtin_amdgcn_s_barrier();

    // ---- epilogue: relu, LDS transpose to H2-image (64KB @ lds+0) -----
    char* img = lds;
#pragma unroll
    for (int mi = 0; mi < 4; ++mi) {
#pragma unroll
      for (int ni = 0; ni < 4; ++ni) {
        const int colL = wc * 64 + ni * 16 + ln15;
        const int basei = (colL >> 6) * 32768 + ((colL >> 3) & 7) * 4096 + (colL & 7) * 2;
#pragma unroll
        for (int j = 0; j < 4; ++j) {
          const int rowL = wr * 64 + mi * 16 + l16 * 4 + j;
          float v = acc[mi][ni][j];
          v = v > 0.f ? v : 0.f;
          *(unsigned short*)(img + basei + rowL * 16) = f2bf(v);
        }
      }
    }
    __syncthreads();
    const char* src = img + tid * 128;
    char* dst = (char*)H2 + (size_t)e * 4194304 +
                (size_t)((n0 >> 6) + (tid >> 8)) * 65536 +
                (size_t)((tid >> 5) & 7) * 8192 +
                (size_t)(m0 + (tid & 31) * 8) * 16;
#pragma unroll
    for (int u = 0; u < 8; ++u)
      *(uint4*)(dst + u * 16) = *(const uint4*)(src + u * 16);
    __syncthreads();   // img fully read before next strip's staging
  }
}

// ---------------- GEMM2 (R8-proven): out[tok] = (H2[e] @ w2[e]) * gate --
#define G2_BX 2
#define G2_BY 8
#define G2_BZ 16
__global__ void __launch_bounds__(512, 2)
gemm2_kernel(const unsigned short* __restrict__ H2, const float* __restrict__ W2,
             const int* __restrict__ s2t, const float* __restrict__ gval,
             float* __restrict__ Out) {
  constexpr int NT = NF / 64;  // 64
  __shared__ __align__(16) char lds[131072];

  const int tid = threadIdx.x;
  const int lane = tid & 63, wid = tid >> 6;
  const int wr = wid >> 1, wc = wid & 1;
  const int ln15 = lane & 15, l16 = lane >> 4;

  const int flat = blockIdx.x + G2_BX * (blockIdx.y + G2_BY * blockIdx.z);
  const int xcd = flat & 7, jj = flat >> 3;      // jj 0..31
  const int e  = xcd * 2 + (jj >> 4);
  const int rr = jj & 15;
  const int by = rr >> 1, bx = rr & 1;
  const int m0 = bx * 256, n0 = by * 128;

  char* const Bb0 = lds + 98304;
  char* const Bb1 = lds + 98304 + 16384;

  const int rb = wid >> 1;
  const int kgw = (wid & 1) * 4;
  const int adst = kgw * 4096 + rb * 1024;
  const char* const Hex = (const char*)H2 + (size_t)e * 4194304 +
                          (size_t)(m0 + rb * 64 + lane) * 16;

  const int c0 = (tid & 31) * 4;
  const int kq = tid >> 5;
  const float* const bsrc = W2 + (size_t)e * NF * DM + (size_t)(kq * 4) * DM + n0 + c0;
  const int kgb = kq >> 1, hb = kq & 1;
  int bwoff[4];
#pragma unroll
  for (int cc = 0; cc < 4; ++cc) bwoff[cc] = kgb * 2048 + pcol(c0 + cc) * 16 + hb * 8;

  int aoff[4], boff[4];
#pragma unroll
  for (int mi = 0; mi < 4; ++mi) aoff[mi] = l16 * 4096 + (wr * 64 + mi * 16 + ln15) * 16;
#pragma unroll
  for (int ni = 0; ni < 4; ++ni) boff[ni] = l16 * 2048 + pcol(wc * 64 + ni * 16 + ln15) * 16;

  f32x4 acc[4][4];
#pragma unroll
  for (int mi = 0; mi < 4; ++mi)
#pragma unroll
    for (int ni = 0; ni < 4; ++ni) acc[mi][ni] = f32x4{0.f, 0.f, 0.f, 0.f};

  float4 breg[4];

  auto ISSUE_B = [&](int kt) {
    const float* bp = bsrc + (size_t)kt * 64 * DM;
#pragma unroll
    for (int r = 0; r < 4; ++r) breg[r] = *(const float4*)(bp + (size_t)r * DM);
  };
  auto ISSUE_A = [&](int Aoff, int kt) {
#pragma unroll
    for (int j = 0; j < 4; ++j)
      gload_lds16(Hex + (size_t)kt * 65536 + (size_t)(kgw + j) * 8192,
                  lds + Aoff + adst + j * 4096);
  };
  auto WRITEB = [&](char* Bbuf) {
    const float* f = (const float*)breg;
#pragma unroll
    for (int cc = 0; cc < 4; ++cc)
      *(uint2*)(Bbuf + bwoff[cc]) =
          make_uint2(pk2(f[0 + cc], f[4 + cc]), pk2(f[8 + cc], f[12 + cc]));
  };
  auto COMPUTE = [&](int Aoff, const char* Bbuf) {
#pragma unroll
    for (int kk = 0; kk < 2; ++kk) {
      bf16x8 af[4], bf[4];
#pragma unroll
      for (int mi = 0; mi < 4; ++mi)
        af[mi] = *(const bf16x8*)(lds + Aoff + kk * 16384 + aoff[mi]);
#pragma unroll
      for (int ni = 0; ni < 4; ++ni)
        bf[ni] = *(const bf16x8*)(Bbuf + kk * 8192 + boff[ni]);
#pragma unroll
      for (int mi = 0; mi < 4; ++mi)
#pragma unroll
        for (int ni = 0; ni < 4; ++ni)
          acc[mi][ni] = __builtin_amdgcn_mfma_f32_16x16x32_bf16(af[mi], bf[ni], acc[mi][ni], 0, 0, 0);
    }
  };

  ISSUE_B(0); ISSUE_A(0, 0);
  WRITEB(Bb0);
  ISSUE_B(1); ISSUE_A(32768, 1);
  asm volatile("s_waitcnt vmcnt(8) lgkmcnt(0)" ::: "memory");
  __builtin_amdgcn_s_barrier();

  int aCur = 0, aNxt = 32768, aNx2 = 65536;
  for (int kt = 0; kt < NT; ++kt) {
    WRITEB((kt & 1) ? Bb0 : Bb1);
    const int tl = (kt + 2 < NT) ? kt + 2 : NT - 1;
    ISSUE_B(tl);
    ISSUE_A(aNx2, tl);
    COMPUTE(aCur, (kt & 1) ? Bb1 : Bb0);
    asm volatile("s_waitcnt vmcnt(8) lgkmcnt(0)" ::: "memory");
    __builtin_amdgcn_s_barrier();
    const int t = aCur; aCur = aNxt; aNxt = aNx2; aNx2 = t;
  }
  asm volatile("s_waitcnt vmcnt(0)" ::: "memory");

#pragma unroll
  for (int mi = 0; mi < 4; ++mi) {
#pragma unroll
    for (int ni = 0; ni < 4; ++ni) {
      const int col = n0 + wc * 64 + ni * 16 + ln15;
#pragma unroll
      for (int j = 0; j < 4; ++j) {
        const int row = m0 + wr * 64 + mi * 16 + l16 * 4 + j;
        const int tk = s2t[e * CAP + row];
        if (tk >= 0)
          Out[(size_t)tk * DM + col] = acc[mi][ni][j] * gval[tk];
      }
    }
  }
}

// ----------------------------- launcher --------------------------------
extern "C" void kernel_launch(void* const* d_in, const int* in_sizes, int n_in,
                              void* d_out, int out_size, void* d_ws, size_t ws_size,
                              hipStream_t stream) {
  (void)in_sizes; (void)n_in; (void)ws_size;
  const float* X  = (const float*)d_in[0];
  const float* Wg = (const float*)d_in[1];
  const float* W1 = (const float*)d_in[2];
  const float* W2 = (const float*)d_in[3];
  float* Out = (float*)d_out;

  char* ws = (char*)d_ws;
  int*   s2t  = (int*)ws;                            // 32 KB
  int*   idx  = (int*)(ws + 32768);
  float* gval = (float*)(ws + 65536);
  unsigned short* Xg = (unsigned short*)(ws + 98304);            // 16 MB blocked gathered
  unsigned short* H2 = (unsigned short*)(ws + 98304 + 16777216); // 64 MB blocked

  zero_kernel<<<2048, 256, 0, stream>>>((float4*)Out, out_size / 4);
  gate_kernel<<<S_TOK / 16, 256, 0, stream>>>(X, Wg, idx, gval);
  scan_kernel<<<1, 1024, 0, stream>>>(idx, s2t);
  gather_kernel<<<512, 256, 0, stream>>>(X, s2t, Xg);
  gemm1_kernel<<<dim3(G1_BX, G1_BY, G1_BZ), 512, 0, stream>>>(Xg, W1, H2);
  gemm2_kernel<<<dim3(G2_BX, G2_BY, G2_BZ), 512, 0, stream>>>(H2, W2, s2t, gval, Out);
}

// Round 15
// 281.044 us; speedup vs baseline: 3.5610x; 1.0050x over previous
//
#include <hip/hip_runtime.h>
#include <cstdint>
#include <cstddef>

#define S_TOK 8192
#define DM    1024
#define NE    16
#define NF    4096
#define CAP   512

typedef __attribute__((ext_vector_type(8))) short bf16x8;
typedef __attribute__((ext_vector_type(4))) float f32x4;

__device__ __forceinline__ unsigned short f2bf(float f) {
  __bf16 b = (__bf16)f;
  return __builtin_bit_cast(unsigned short, b);
}
__device__ __forceinline__ unsigned pk2(float a, float b) {
  return (unsigned)f2bf(a) | ((unsigned)f2bf(b) << 16);
}
// bank-spread for the B [kg][col][16B] LDS layout
__device__ __forceinline__ int pcol(int c) { return c ^ ((c >> 3) & 7); }

__device__ __forceinline__ void gload_lds16(const void* g, void* l) {
  __builtin_amdgcn_global_load_lds(
      (const __attribute__((address_space(1))) void*)g,
      (__attribute__((address_space(3))) void*)l, 16, 0, 0);
}

// ---------------- fast zero of d_out ------------------------------------
__global__ void __launch_bounds__(256)
zero_kernel(float4* __restrict__ Out, int n4) {
  const int stride = gridDim.x * 256;
  for (int i = blockIdx.x * 256 + threadIdx.x; i < n4; i += stride)
    Out[i] = float4{0.f, 0.f, 0.f, 0.f};
}

// ---------------- gating: logits fp32, softmax, argmax -----------------
__global__ void __launch_bounds__(256)
gate_kernel(const float* __restrict__ X, const float* __restrict__ Wg,
            int* __restrict__ idx, float* __restrict__ gval) {
  const int tid  = threadIdx.x;
  const int lane = tid & 63;
  const int wid  = tid >> 6;
  const int e = lane & 15, q = lane >> 4;
  const int t0 = blockIdx.x * 16 + wid * 4;
  const int mbase = q * 256;

  const float* xp0 = X + (size_t)(t0 + 0) * DM + mbase;
  const float* xp1 = X + (size_t)(t0 + 1) * DM + mbase;
  const float* xp2 = X + (size_t)(t0 + 2) * DM + mbase;
  const float* xp3 = X + (size_t)(t0 + 3) * DM + mbase;
  const float* wp  = Wg + (size_t)mbase * NE + e;

  float a0 = 0.f, a1 = 0.f, a2 = 0.f, a3 = 0.f;
#pragma unroll 4
  for (int i = 0; i < 64; ++i) {
    float4 x0 = *(const float4*)(xp0 + i * 4);
    float4 x1 = *(const float4*)(xp1 + i * 4);
    float4 x2 = *(const float4*)(xp2 + i * 4);
    float4 x3 = *(const float4*)(xp3 + i * 4);
    float w0 = wp[(i * 4 + 0) * NE];
    float w1 = wp[(i * 4 + 1) * NE];
    float w2 = wp[(i * 4 + 2) * NE];
    float w3 = wp[(i * 4 + 3) * NE];
    a0 = fmaf(x0.x, w0, fmaf(x0.y, w1, fmaf(x0.z, w2, fmaf(x0.w, w3, a0))));
    a1 = fmaf(x1.x, w0, fmaf(x1.y, w1, fmaf(x1.z, w2, fmaf(x1.w, w3, a1))));
    a2 = fmaf(x2.x, w0, fmaf(x2.y, w1, fmaf(x2.z, w2, fmaf(x2.w, w3, a2))));
    a3 = fmaf(x3.x, w0, fmaf(x3.y, w1, fmaf(x3.z, w2, fmaf(x3.w, w3, a3))));
  }
#pragma unroll
  for (int s = 16; s < 64; s <<= 1) {
    a0 += __shfl_xor(a0, s, 64);
    a1 += __shfl_xor(a1, s, 64);
    a2 += __shfl_xor(a2, s, 64);
    a3 += __shfl_xor(a3, s, 64);
  }
  float l = (q == 0) ? a0 : (q == 1) ? a1 : (q == 2) ? a2 : a3;
  float bv = l; int bi = e;
#pragma unroll
  for (int s = 1; s < 16; s <<= 1) {
    float ov = __shfl_xor(bv, s, 16);
    int   oi = __shfl_xor(bi, s, 16);
    if (ov > bv || (ov == bv && oi < bi)) { bv = ov; bi = oi; }
  }
  float p  = expf(l - bv);
  float sm = p;
#pragma unroll
  for (int s = 1; s < 16; s <<= 1) sm += __shfl_xor(sm, s, 16);
  if (e == 0) {
    idx[t0 + q]  = bi;
    gval[t0 + q] = 1.0f / sm;
  }
}

// ---------------- routing scan: capacity-limited slot assignment -------
__global__ void __launch_bounds__(1024)
scan_kernel(const int* __restrict__ idx, int* __restrict__ s2t) {
  const int tid = threadIdx.x;
#pragma unroll
  for (int k = 0; k < 8; ++k) s2t[tid + k * 1024] = -1;
  __shared__ int base[16];
  __shared__ int wavecnt[16][16];
  if (tid < 16) base[tid] = 0;
  __syncthreads();
  const int wid = tid >> 6, lane = tid & 63;
  const unsigned long long ltmask = (1ull << lane) - 1ull;
  for (int c = 0; c < 8; ++c) {
    const int t = c * 1024 + tid;
    const int e = idx[t];
    int rank = 0;
#pragma unroll
    for (int ee = 0; ee < 16; ++ee) {
      unsigned long long m = __ballot(e == ee);
      if (lane == 0) wavecnt[wid][ee] = __popcll(m);
      if (ee == e) rank = __popcll(m & ltmask);
    }
    __syncthreads();
    if (tid < 16) {
      int s = base[tid];
#pragma unroll
      for (int w = 0; w < 16; ++w) { int cc = wavecnt[w][tid]; wavecnt[w][tid] = s; s += cc; }
      base[tid] = s;
    }
    __syncthreads();
    const int loc = wavecnt[wid][e] + rank;
    if (loc < CAP) s2t[e * CAP + loc] = t;
    __syncthreads();
  }
}

// ---------------- gather + cvt: X fp32 rows -> blocked gathered bf16 ----
// Xg layout: [e][kt(16)][kg(8)][slot(512)][16B]; 1 MB/expert, 16 MB.
__global__ void __launch_bounds__(256)
gather_kernel(const float* __restrict__ X, const int* __restrict__ s2t,
              unsigned short* __restrict__ Xg) {
  const int tid = threadIdx.x;
  const int d  = tid & 127;           // 8 floats per thread
  const int sl = tid >> 7;            // 0..1
  const int s0 = blockIdx.x * 16;     // 16 slots per block
#pragma unroll 2
  for (int p = 0; p < 8; ++p) {
    const int s = s0 + p * 2 + sl;
    const int tok = s2t[s];
    uint4 w;
    if (tok >= 0) {
      const float* xp = X + (size_t)tok * DM + d * 8;
      float4 v0 = *(const float4*)xp;
      float4 v1 = *(const float4*)(xp + 4);
      w = make_uint4(pk2(v0.x, v0.y), pk2(v0.z, v0.w),
                     pk2(v1.x, v1.y), pk2(v1.z, v1.w));
    } else {
      w = make_uint4(0u, 0u, 0u, 0u);
    }
    char* dst = (char*)Xg + (size_t)(s >> 9) * 1048576 +
                (size_t)(d >> 3) * 65536 + (size_t)(d & 7) * 8192 +
                (size_t)(s & 511) * 16;
    *(uint4*)dst = w;
  }
}

// H2 layout: [e][kt(64)][kg(8)][row(512)][8 bf16]; per-expert 4 MB.

// ---------------- GEMM1 (R15): 256x256 tile, 8 waves (2Mx4N) -----------
// Raises arithmetic intensity per LDS byte: reads/iter 192 KB for 2x the
// FLOPs of the 256x128 tile (reuse A x4 -> x4, B x... net -25%/FLOP).
// LDS 128 KB: A dbuf 2x32K @0/@32768 (gload_lds, depth-1, issued FIRST
// so vmcnt(8) retires A while B(kt+2) flies); B dbuf 2x32K @65536/@98304
// (reg-staged fp32->bf16, 1-iter slack). R8-proven sync: 1 barrier/iter.
#define G1_BX 2
#define G1_BY 16
#define G1_BZ 16
__global__ void __launch_bounds__(512, 2)
gemm1_kernel(const unsigned short* __restrict__ Xg, const float* __restrict__ W1,
             unsigned short* __restrict__ H2) {
  constexpr int NT = DM / 64;  // 16
  __shared__ __align__(16) char lds[131072];

  const int tid = threadIdx.x;
  const int lane = tid & 63, wid = tid >> 6;
  const int wr = wid >> 2, wc = wid & 3;     // 2M x 4N, per-wave 128x64
  const int ln15 = lane & 15, l16 = lane >> 4;

  const int flat = blockIdx.x + G1_BX * (blockIdx.y + G1_BY * blockIdx.z);
  const int xcd = flat & 7, jj = flat >> 3;  // jj 0..63
  const int e  = xcd * 2 + (jj >> 5);
  const int rr = jj & 31;
  const int by = rr >> 1, bx = rr & 1;
  const int m0 = bx * 256, n0 = by * 256;

  char* const Bb0 = lds + 65536;
  char* const Bb1 = lds + 98304;

  // A staging: wave covers rows rb*64+lane (rb=wid>>1), kg=(wid&1)*4+j
  const int rb = wid >> 1;
  const int kgw = (wid & 1) * 4;
  const int adst = kgw * 4096 + rb * 1024;
  const char* const aSrc = (const char*)Xg + (size_t)e * 1048576 +
                           (size_t)(m0 + rb * 64 + lane) * 16;

  // B staging: cols c0..c0+3, k-rows kq*8..+7
  const int c0 = (tid & 63) * 4;
  const int kq = tid >> 6;                   // 0..7
  const float* const bsrc = W1 + (size_t)e * DM * NF + (size_t)(kq * 8) * NF + n0 + c0;
  int bwoff[4];
#pragma unroll
  for (int cc = 0; cc < 4; ++cc) bwoff[cc] = kq * 4096 + pcol(c0 + cc) * 16;

  int aoff[8], boff[4];
#pragma unroll
  for (int mi = 0; mi < 8; ++mi)
    aoff[mi] = l16 * 4096 + (wr * 128 + mi * 16 + ln15) * 16;
#pragma unroll
  for (int ni = 0; ni < 4; ++ni)
    boff[ni] = l16 * 4096 + pcol(wc * 64 + ni * 16 + ln15) * 16;

  f32x4 acc[8][4];
#pragma unroll
  for (int mi = 0; mi < 8; ++mi)
#pragma unroll
    for (int ni = 0; ni < 4; ++ni) acc[mi][ni] = f32x4{0.f, 0.f, 0.f, 0.f};

  float4 breg[8];

  auto ISSUE_B = [&](int kt) {
    const float* bp = bsrc + (size_t)kt * 64 * NF;
#pragma unroll
    for (int r = 0; r < 8; ++r) breg[r] = *(const float4*)(bp + (size_t)r * NF);
  };
  auto ISSUE_A = [&](int Aoff, int kt) {
#pragma unroll
    for (int j = 0; j < 4; ++j)
      gload_lds16(aSrc + (size_t)kt * 65536 + (size_t)(kgw + j) * 8192,
                  lds + Aoff + adst + j * 4096);
  };
  auto WRITEB = [&](char* Bbuf) {
    const float* f = (const float*)breg;
#pragma unroll
    for (int cc = 0; cc < 4; ++cc)
      *(uint4*)(Bbuf + bwoff[cc]) =
          make_uint4(pk2(f[0 * 4 + cc], f[1 * 4 + cc]), pk2(f[2 * 4 + cc], f[3 * 4 + cc]),
                     pk2(f[4 * 4 + cc], f[5 * 4 + cc]), pk2(f[6 * 4 + cc], f[7 * 4 + cc]));
  };
  auto COMPUTE = [&](int Aoff, const char* Bbuf) {
#pragma unroll
    for (int kk = 0; kk < 2; ++kk) {
      bf16x8 af[8], bf[4];
#pragma unroll
      for (int mi = 0; mi < 8; ++mi)
        af[mi] = *(const bf16x8*)(lds + Aoff + kk * 16384 + aoff[mi]);
#pragma unroll
      for (int ni = 0; ni < 4; ++ni)
        bf[ni] = *(const bf16x8*)(Bbuf + kk * 16384 + boff[ni]);
      __builtin_amdgcn_s_setprio(1);
#pragma unroll
      for (int mi = 0; mi < 8; ++mi)
#pragma unroll
        for (int ni = 0; ni < 4; ++ni)
          acc[mi][ni] = __builtin_amdgcn_mfma_f32_16x16x32_bf16(af[mi], bf[ni], acc[mi][ni], 0, 0, 0);
      __builtin_amdgcn_s_setprio(0);
    }
  };

  // prologue: A(0)->buf0; Bb0 <- B(0); breg <- B(1)
  ISSUE_A(0, 0);
  ISSUE_B(0);
  WRITEB(Bb0);                      // waits B(0); retires A(0) too (older)
  ISSUE_B(1);
  asm volatile("s_waitcnt vmcnt(8) lgkmcnt(0)" ::: "memory");
  __builtin_amdgcn_s_barrier();

#pragma unroll 1
  for (int kt = 0; kt < NT; ++kt) {
    const int Acur = (kt & 1) ? 32768 : 0;
    const int Anxt = (kt & 1) ? 0 : 32768;
    ISSUE_A(Anxt, (kt + 1 < NT) ? kt + 1 : NT - 1);     // 4 gloads (oldest)
    WRITEB((kt & 1) ? Bb0 : Bb1);                        // B(kt+1) -> other buf
    ISSUE_B((kt + 2 < NT) ? kt + 2 : NT - 1);            // 8 loads (newest)
    COMPUTE(Acur, (kt & 1) ? Bb1 : Bb0);
    asm volatile("s_waitcnt vmcnt(8) lgkmcnt(0)" ::: "memory");
    __builtin_amdgcn_s_barrier();
  }
  asm volatile("s_waitcnt vmcnt(0)" ::: "memory");
  __builtin_amdgcn_s_barrier();

  // ---- epilogue: relu + transpose to H2-image, two 64-KB halves -------
  char* img = lds;
#pragma unroll 1
  for (int h = 0; h < 2; ++h) {
    if ((wc >> 1) == h) {
#pragma unroll
      for (int mi = 0; mi < 8; ++mi) {
#pragma unroll
        for (int ni = 0; ni < 4; ++ni) {
          const int colL = (wc & 1) * 64 + ni * 16 + ln15;
          const int basei = (colL >> 6) * 32768 + ((colL >> 3) & 7) * 4096 + (colL & 7) * 2;
#pragma unroll
          for (int j = 0; j < 4; ++j) {
            const int rowL = wr * 128 + mi * 16 + l16 * 4 + j;
            float v = acc[mi][ni][j];
            v = v > 0.f ? v : 0.f;
            *(unsigned short*)(img + basei + rowL * 16) = f2bf(v);
          }
        }
      }
    }
    __syncthreads();
    const char* src = img + tid * 128;
    char* dst = (char*)H2 + (size_t)e * 4194304 +
                (size_t)((n0 >> 6) + h * 2 + (tid >> 8)) * 65536 +
                (size_t)((tid >> 5) & 7) * 8192 +
                (size_t)(m0 + (tid & 31) * 8) * 16;
#pragma unroll
    for (int u = 0; u < 8; ++u)
      *(uint4*)(dst + u * 16) = *(const uint4*)(src + u * 16);
    __syncthreads();
  }
}

// ---------------- GEMM2 (R8-proven): out[tok] = (H2[e] @ w2[e]) * gate --
#define G2_BX 2
#define G2_BY 8
#define G2_BZ 16
__global__ void __launch_bounds__(512, 2)
gemm2_kernel(const unsigned short* __restrict__ H2, const float* __restrict__ W2,
             const int* __restrict__ s2t, const float* __restrict__ gval,
             float* __restrict__ Out) {
  constexpr int NT = NF / 64;  // 64
  __shared__ __align__(16) char lds[131072];

  const int tid = threadIdx.x;
  const int lane = tid & 63, wid = tid >> 6;
  const int wr = wid >> 1, wc = wid & 1;
  const int ln15 = lane & 15, l16 = lane >> 4;

  const int flat = blockIdx.x + G2_BX * (blockIdx.y + G2_BY * blockIdx.z);
  const int xcd = flat & 7, jj = flat >> 3;      // jj 0..31
  const int e  = xcd * 2 + (jj >> 4);
  const int rr = jj & 15;
  const int by = rr >> 1, bx = rr & 1;
  const int m0 = bx * 256, n0 = by * 128;

  char* const Bb0 = lds + 98304;
  char* const Bb1 = lds + 98304 + 16384;

  const int rb = wid >> 1;
  const int kgw = (wid & 1) * 4;
  const int adst = kgw * 4096 + rb * 1024;
  const char* const Hex = (const char*)H2 + (size_t)e * 4194304 +
                          (size_t)(m0 + rb * 64 + lane) * 16;

  const int c0 = (tid & 31) * 4;
  const int kq = tid >> 5;
  const float* const bsrc = W2 + (size_t)e * NF * DM + (size_t)(kq * 4) * DM + n0 + c0;
  const int kgb = kq >> 1, hb = kq & 1;
  int bwoff[4];
#pragma unroll
  for (int cc = 0; cc < 4; ++cc) bwoff[cc] = kgb * 2048 + pcol(c0 + cc) * 16 + hb * 8;

  int aoff[4], boff[4];
#pragma unroll
  for (int mi = 0; mi < 4; ++mi) aoff[mi] = l16 * 4096 + (wr * 64 + mi * 16 + ln15) * 16;
#pragma unroll
  for (int ni = 0; ni < 4; ++ni) boff[ni] = l16 * 2048 + pcol(wc * 64 + ni * 16 + ln15) * 16;

  f32x4 acc[4][4];
#pragma unroll
  for (int mi = 0; mi < 4; ++mi)
#pragma unroll
    for (int ni = 0; ni < 4; ++ni) acc[mi][ni] = f32x4{0.f, 0.f, 0.f, 0.f};

  float4 breg[4];

  auto ISSUE_B = [&](int kt) {
    const float* bp = bsrc + (size_t)kt * 64 * DM;
#pragma unroll
    for (int r = 0; r < 4; ++r) breg[r] = *(const float4*)(bp + (size_t)r * DM);
  };
  auto ISSUE_A = [&](int Aoff, int kt) {
#pragma unroll
    for (int j = 0; j < 4; ++j)
      gload_lds16(Hex + (size_t)kt * 65536 + (size_t)(kgw + j) * 8192,
                  lds + Aoff + adst + j * 4096);
  };
  auto WRITEB = [&](char* Bbuf) {
    const float* f = (const float*)breg;
#pragma unroll
    for (int cc = 0; cc < 4; ++cc)
      *(uint2*)(Bbuf + bwoff[cc]) =
          make_uint2(pk2(f[0 + cc], f[4 + cc]), pk2(f[8 + cc], f[12 + cc]));
  };
  auto COMPUTE = [&](int Aoff, const char* Bbuf) {
#pragma unroll
    for (int kk = 0; kk < 2; ++kk) {
      bf16x8 af[4], bf[4];
#pragma unroll
      for (int mi = 0; mi < 4; ++mi)
        af[mi] = *(const bf16x8*)(lds + Aoff + kk * 16384 + aoff[mi]);
#pragma unroll
      for (int ni = 0; ni < 4; ++ni)
        bf[ni] = *(const bf16x8*)(Bbuf + kk * 8192 + boff[ni]);
#pragma unroll
      for (int mi = 0; mi < 4; ++mi)
#pragma unroll
        for (int ni = 0; ni < 4; ++ni)
          acc[mi][ni] = __builtin_amdgcn_mfma_f32_16x16x32_bf16(af[mi], bf[ni], acc[mi][ni], 0, 0, 0);
    }
  };

  ISSUE_B(0); ISSUE_A(0, 0);
  WRITEB(Bb0);
  ISSUE_B(1); ISSUE_A(32768, 1);
  asm volatile("s_waitcnt vmcnt(8) lgkmcnt(0)" ::: "memory");
  __builtin_amdgcn_s_barrier();

  int aCur = 0, aNxt = 32768, aNx2 = 65536;
  for (int kt = 0; kt < NT; ++kt) {
    WRITEB((kt & 1) ? Bb0 : Bb1);
    const int tl = (kt + 2 < NT) ? kt + 2 : NT - 1;
    ISSUE_B(tl);
    ISSUE_A(aNx2, tl);
    COMPUTE(aCur, (kt & 1) ? Bb1 : Bb0);
    asm volatile("s_waitcnt vmcnt(8) lgkmcnt(0)" ::: "memory");
    __builtin_amdgcn_s_barrier();
    const int t = aCur; aCur = aNxt; aNxt = aNx2; aNx2 = t;
  }
  asm volatile("s_waitcnt vmcnt(0)" ::: "memory");

#pragma unroll
  for (int mi = 0; mi < 4; ++mi) {
#pragma unroll
    for (int ni = 0; ni < 4; ++ni) {
      const int col = n0 + wc * 64 + ni * 16 + ln15;
#pragma unroll
      for (int j = 0; j < 4; ++j) {
        const int row = m0 + wr * 64 + mi * 16 + l16 * 4 + j;
        const int tk = s2t[e * CAP + row];
        if (tk >= 0)
          Out[(size_t)tk * DM + col] = acc[mi][ni][j] * gval[tk];
      }
    }
  }
}

// ----------------------------- launcher --------------------------------
extern "C" void kernel_launch(void* const* d_in, const int* in_sizes, int n_in,
                              void* d_out, int out_size, void* d_ws, size_t ws_size,
                              hipStream_t stream) {
  (void)in_sizes; (void)n_in; (void)ws_size;
  const float* X  = (const float*)d_in[0];
  const float* Wg = (const float*)d_in[1];
  const float* W1 = (const float*)d_in[2];
  const float* W2 = (const float*)d_in[3];
  float* Out = (float*)d_out;

  char* ws = (char*)d_ws;
  int*   s2t  = (int*)ws;                            // 32 KB
  int*   idx  = (int*)(ws + 32768);
  float* gval = (float*)(ws + 65536);
  unsigned short* Xg = (unsigned short*)(ws + 98304);            // 16 MB blocked gathered
  unsigned short* H2 = (unsigned short*)(ws + 98304 + 16777216); // 64 MB blocked

  zero_kernel<<<2048, 256, 0, stream>>>((float4*)Out, out_size / 4);
  gate_kernel<<<S_TOK / 16, 256, 0, stream>>>(X, Wg, idx, gval);
  scan_kernel<<<1, 1024, 0, stream>>>(idx, s2t);
  gather_kernel<<<512, 256, 0, stream>>>(X, s2t, Xg);
  gemm1_kernel<<<dim3(G1_BX, G1_BY, G1_BZ), 512, 0, stream>>>(Xg, W1, H2);
  gemm2_kernel<<<dim3(G2_BX, G2_BY, G2_BZ), 512, 0, stream>>>(H2, W2, s2t, gval, Out);
}